// Round 3
// baseline (102.669 us; speedup 1.0000x reference)
//
#include <hip/hip_runtime.h>

// Problem: B=16384, X_DIM=1024, K=64, fp32 in/out.
// out[b] = 0.5 * ( sum_k (x_b . V[:,k])^2  -  sum_i x_bi^2 w_i ),  w_i = sum_k V[i][k]^2
//
// R18 = R16 resubmitted (2nd time). Both prior attempts died to
// "MI355X container failed twice" with no timing fields -- a pre-push
// broker failure, not a kernel failure. Full OOB audit of this source
// found every access in-bounds (xrow<=1023, wc<=1023, bh<=131072B,
// comb<=7614) and no hang path; source is a strict subset of R15 which ran.
//
// R16 rationale: x has ZERO reuse -- wave w consumes only cols
// [128w,128w+128) of the block's 16 rows, each 32B chunk read by exactly one
// lane, once. R15's DMA->LDS->VGPR round trip (66 KB xbuf, 64 DMAs, PITCH
// banking) and its full-block vmcnt(0)+barrier drain were pure overhead that
// serialized each block's memory phase against compute (2 blocks/CU).
// Now: A-fragments load straight from global (2x dwordx4 per i-tile,
// 32B-aligned), w loads from the 4 KB L2-hot wc. No barrier until the
// combine write->read handoff. LDS 71 KB -> ~31 KB. MFMA / z-path / repack /
// combine are bit-identical to R15.

typedef short short8 __attribute__((ext_vector_type(8)));   // 8 bf16 = 4 VGPRs
typedef float f32x4 __attribute__((ext_vector_type(4)));

constexpr int XD = 1024;
constexpr int KD = 64;

static __device__ __forceinline__ unsigned short f2bf(float f) {
    union { float f; unsigned u; } v; v.f = f;
    unsigned r = v.u + 0x7FFFu + ((v.u >> 16) & 1u);   // RNE
    return (unsigned short)(r >> 16);
}
static __device__ __forceinline__ unsigned fbits(float f) {
    union { float f; unsigned u; } v; v.f = f; return v.u;
}

// ---- prep: blocks 0..31 build bf16 B-fragments (RNE); 32..35 build w ----
// B-fragment layout (mfma_f32_16x16x32_bf16): lane l holds B[k=(l>>4)*8+j][n=l&15]
// ws: bh @ 0 (131072 B) | wc @ 131072 (4096 B)
__global__ void prep_kernel(const float* __restrict__ v,
                            unsigned short* __restrict__ bh,
                            float* __restrict__ wc) {
    if (blockIdx.x < 32) {
        int idx = blockIdx.x * 256 + threadIdx.x;
        int it = idx >> 8;
        int r  = idx & 255;
        int t  = r >> 6;
        int l  = r & 63;
        int q  = l >> 4, m = l & 15;
        int base_i = it * 32 + q * 8;
        int n = t * 16 + m;
        size_t fo = ((size_t)(it * 4 + t) * 64 + l) * 8;
#pragma unroll
        for (int j = 0; j < 8; ++j) {
            float val = v[(size_t)(base_i + j) * KD + n];
            bh[fo + j] = f2bf(val);
        }
    } else {
        int i = (blockIdx.x - 32) * 256 + threadIdx.x;   // 0..1023
        const f32x4* vp = (const f32x4*)(v + (size_t)i * KD);
        f32x4 tv[16];
#pragma unroll
        for (int qq = 0; qq < 16; ++qq) tv[qq] = vp[qq];
        float s = 0.f;
#pragma unroll
        for (int qq = 0; qq < 16; ++qq) {
            s = fmaf(tv[qq].x, tv[qq].x, s); s = fmaf(tv[qq].y, tv[qq].y, s);
            s = fmaf(tv[qq].z, tv[qq].z, s); s = fmaf(tv[qq].w, tv[qq].w, s);
        }
        wc[i] = s;
    }
}

// ---- main: 512 thr / 8 waves; block = 16 full rows; wave = 4 i-tiles ----
__global__ __launch_bounds__(512, 4)
void cross_r18(const float* __restrict__ x,
               const unsigned short* __restrict__ bh,
               const float* __restrict__ wc,
               float* __restrict__ out) {
    // Dedicated combine area. 7 waves x 64 lanes x 17 floats
    // (17-stride keeps R15's bank spread) = 30464 B.
    __shared__ float comb[7 * 64 * 17];
    __shared__ float zb[7][16];        //  448 B   (total ~30.9 KB)

    const int tid = threadIdx.x;
    const int l = tid & 63;
    const int w = __builtin_amdgcn_readfirstlane(tid >> 6);   // wave 0..7
    const int q = l >> 4, m = l & 15;
    const int row0 = blockIdx.x * 16;

    // Lane's A-row base: row m of this block's 16 rows (4 KB-aligned rows;
    // col offsets are multiples of 8 floats -> all loads 32B-aligned).
    const float* xrow = x + (size_t)(row0 + m) * XD;

    // ---- compute: wave w -> i-tiles 4w .. 4w+3, no pre-barriers ----
    f32x4 c4[4];
#pragma unroll
    for (int t = 0; t < 4; ++t) c4[t] = f32x4{0.f, 0.f, 0.f, 0.f};
    float z = 0.f;

    const short8* bhp = (const short8*)bh;

#pragma unroll
    for (int ii = 0; ii < 4; ++ii) {
        const int it = w * 4 + ii;
        const int col = it * 32 + q * 8;
        const size_t fbase = (size_t)(it * 4) * 64 + l;

        // A source: x row m, floats col..col+7, straight from global.
        f32x4 xa = *(const f32x4*)(xrow + col);
        f32x4 xb = *(const f32x4*)(xrow + col + 4);

        // w source: 4 KB wc, L2/L1-hot (read by every block).
        f32x4 wa = *(const f32x4*)(wc + col);
        f32x4 wb = *(const f32x4*)(wc + col + 4);

        float xs[8] = {xa.x, xa.y, xa.z, xa.w, xb.x, xb.y, xb.z, xb.w};
        z = fmaf(xs[0]*xs[0], wa.x, z); z = fmaf(xs[1]*xs[1], wa.y, z);
        z = fmaf(xs[2]*xs[2], wa.z, z); z = fmaf(xs[3]*xs[3], wa.w, z);
        z = fmaf(xs[4]*xs[4], wb.x, z); z = fmaf(xs[5]*xs[5], wb.y, z);
        z = fmaf(xs[6]*xs[6], wb.z, z); z = fmaf(xs[7]*xs[7], wb.w, z);

        // RNE bf16 pack of x (pairwise via v_perm)
        unsigned ahp[4];
#pragma unroll
        for (int jp = 0; jp < 4; ++jp) {
            unsigned u0 = fbits(xs[2 * jp]);
            unsigned u1 = fbits(xs[2 * jp + 1]);
            u0 += 0x7FFFu + ((u0 >> 16) & 1u);
            u1 += 0x7FFFu + ((u1 >> 16) & 1u);
            ahp[jp] = __builtin_amdgcn_perm(u1, u0, 0x07060302u);  // {hi16(u1),hi16(u0)}
        }
        short8 ah;
#pragma unroll
        for (int jp = 0; jp < 4; ++jp) {
            ah[2*jp]   = (short)(ahp[jp] & 0xFFFF);
            ah[2*jp+1] = (short)(ahp[jp] >> 16);
        }

        // 4 independent MFMA chains (one per col-tile t)
#pragma unroll
        for (int t = 0; t < 4; ++t) {
            short8 vh = bhp[fbase + (size_t)t * 64];
            c4[t] = __builtin_amdgcn_mfma_f32_16x16x32_bf16(ah, vh, c4[t], 0, 0, 0);
        }
    }

    // z: sum over q-chunks -> full-q partial z for row m (this wave's i-range)
    z += __shfl_xor(z, 16);
    z += __shfl_xor(z, 32);

    if (w > 0) {
        const int s = w - 1;
#pragma unroll
        for (int t = 0; t < 4; ++t)
#pragma unroll
            for (int r = 0; r < 4; ++r) comb[(s * 64 + l) * 17 + t * 4 + r] = c4[t][r];
        if (l < 16) zb[s][l] = z;
    }
    __syncthreads();

    if (w == 0) {
#pragma unroll
        for (int s = 0; s < 7; ++s) {
#pragma unroll
            for (int t = 0; t < 4; ++t)
#pragma unroll
                for (int r = 0; r < 4; ++r) c4[t][r] += comb[(s * 64 + l) * 17 + t * 4 + r];
            z += zb[s][m];
        }

        // C layout: col = l&15, row = q*4 + reg
        float p[4] = {0.f, 0.f, 0.f, 0.f};
#pragma unroll
        for (int r = 0; r < 4; ++r)
#pragma unroll
            for (int t = 0; t < 4; ++t) p[r] = fmaf(c4[t][r], c4[t][r], p[r]);
#pragma unroll
        for (int mask = 1; mask < 16; mask <<= 1)
#pragma unroll
            for (int r = 0; r < 4; ++r) p[r] += __shfl_xor(p[r], mask);

        float zrow = __shfl(z, q * 4 + m, 16);
        if (m < 4) out[row0 + q * 4 + m] = 0.5f * (p[m] - zrow);
    }
}

extern "C" void kernel_launch(void* const* d_in, const int* in_sizes, int n_in,
                              void* d_out, int out_size, void* d_ws, size_t ws_size,
                              hipStream_t stream) {
    const float* x = (const float*)d_in[0];      // (16384, 1024) fp32
    const float* v = (const float*)d_in[1];      // (1024, 64) fp32
    float* out = (float*)d_out;                  // (16384, 1) fp32

    unsigned short* bh = (unsigned short*)d_ws;                    // 131072 B
    float* wc = (float*)((char*)d_ws + 131072);                    //   4096 B

    const int B = in_sizes[0] / XD;              // 16384

    hipLaunchKernelGGL(prep_kernel, dim3(36), dim3(256), 0, stream, v, bh, wc);
    hipLaunchKernelGGL(cross_r18, dim3(B / 16), dim3(512), 0, stream,
                       x, bh, wc, out);
}

// Round 4
// 99.781 us; speedup vs baseline: 1.0289x; 1.0289x over previous
//
#include <hip/hip_runtime.h>

// Problem: B=16384, X_DIM=1024, K=64, fp32 in/out.
// out[b] = 0.5 * ( sum_k (x_b . V[:,k])^2  -  sum_i x_bi^2 w_i ),  w_i = sum_k V[i][k]^2
//
// R19 = wave-local DMA staging (hybrid of R15 and R16).
//  Post-mortem R16 (102.7 vs R15 97.8): direct-global A-gather scatters each
//  dwordx4 across 32 half-used cache lines (2x TA cycles) and exposes HBM
//  latency per wave; the DMA staging was NOT the overhead -- the block-wide
//  vmcnt(0)+barrier rendezvous was.
//  R19: each wave DMAs exactly its own 16x128-float panel (8x contiguous 1KB
//  global_load_lds_dwordx4 into its private 8KB LDS region), then a
//  WAVE-LOCAL s_waitcnt vmcnt(0). No __syncthreads before compute.
//  DMA dest must be linear -> bank spread via both-sides XOR swizzle (m173):
//  global SOURCE address pre-swizzled with ((row&7)<<4), LDS linear, reads
//  apply the same XOR. b128 reads land uniformly at the 8-words/bank floor.
//  comb overlays xbuf (barrier before+after overlay writes). LDS ~64.5 KB ->
//  2 blocks/CU. z-path / repack / MFMA / combine identical to R15/R16.

typedef short short8 __attribute__((ext_vector_type(8)));   // 8 bf16 = 4 VGPRs
typedef float f32x4 __attribute__((ext_vector_type(4)));

constexpr int XD = 1024;
constexpr int KD = 64;

static __device__ __forceinline__ unsigned short f2bf(float f) {
    union { float f; unsigned u; } v; v.f = f;
    unsigned r = v.u + 0x7FFFu + ((v.u >> 16) & 1u);   // RNE
    return (unsigned short)(r >> 16);
}
static __device__ __forceinline__ unsigned fbits(float f) {
    union { float f; unsigned u; } v; v.f = f; return v.u;
}
static __device__ __forceinline__ void load_lds16(const float* g, float* l) {
    __builtin_amdgcn_global_load_lds(
        (const __attribute__((address_space(1))) unsigned int*)g,
        (__attribute__((address_space(3))) unsigned int*)l,
        16, 0, 0);   // 16 B/lane: emits global_load_lds_dwordx4
}

// ---- prep: blocks 0..31 build bf16 B-fragments (RNE); 32..35 build w ----
// B-fragment layout (mfma_f32_16x16x32_bf16): lane l holds B[k=(l>>4)*8+j][n=l&15]
// ws: bh @ 0 (131072 B) | wc @ 131072 (4096 B)
__global__ void prep_kernel(const float* __restrict__ v,
                            unsigned short* __restrict__ bh,
                            float* __restrict__ wc) {
    if (blockIdx.x < 32) {
        int idx = blockIdx.x * 256 + threadIdx.x;
        int it = idx >> 8;
        int r  = idx & 255;
        int t  = r >> 6;
        int l  = r & 63;
        int q  = l >> 4, m = l & 15;
        int base_i = it * 32 + q * 8;
        int n = t * 16 + m;
        size_t fo = ((size_t)(it * 4 + t) * 64 + l) * 8;
#pragma unroll
        for (int j = 0; j < 8; ++j) {
            float val = v[(size_t)(base_i + j) * KD + n];
            bh[fo + j] = f2bf(val);
        }
    } else {
        int i = (blockIdx.x - 32) * 256 + threadIdx.x;   // 0..1023
        const f32x4* vp = (const f32x4*)(v + (size_t)i * KD);
        f32x4 tv[16];
#pragma unroll
        for (int qq = 0; qq < 16; ++qq) tv[qq] = vp[qq];
        float s = 0.f;
#pragma unroll
        for (int qq = 0; qq < 16; ++qq) {
            s = fmaf(tv[qq].x, tv[qq].x, s); s = fmaf(tv[qq].y, tv[qq].y, s);
            s = fmaf(tv[qq].z, tv[qq].z, s); s = fmaf(tv[qq].w, tv[qq].w, s);
        }
        wc[i] = s;
    }
}

// ---- main: 512 thr / 8 waves; block = 16 full rows; wave = 4 i-tiles ----
__global__ __launch_bounds__(512, 4)
void cross_r19(const float* __restrict__ x,
               const unsigned short* __restrict__ bh,
               const float* __restrict__ wc,
               float* __restrict__ out) {
    // Per-wave x panel: wave w owns xbuf[w] = [16 rows][128 floats] = 8 KB.
    // Linear layout (DMA-written); data at linear byte L holds logical byte
    // L ^ ((row&7)<<4), row = L>>9 (source pre-swizzled). Total 64 KB; the
    // front 30.5 KB is reused as the combine area after a barrier.
    __shared__ __align__(16) float xbuf[8][16][128];
    __shared__ float zb[7][16];        //  448 B   (total ~64.5 KB -> 2 blocks/CU)

    const int tid = threadIdx.x;
    const int l = tid & 63;
    const int w = __builtin_amdgcn_readfirstlane(tid >> 6);   // wave 0..7
    const int q = l >> 4, m = l & 15;
    const int row0 = blockIdx.x * 16;

    // ---- stage this wave's panel: 8 contiguous 1-KB DMAs, swizzled source ----
    // DMA j writes LDS bytes [w*8192 + j*1024, +1024) = rows 2j,2j+1 (linear,
    // HW adds lane*16 to the wave-uniform dest). Source: lane l supplies the
    // data belonging at logical col-byte ((l&31)*16) ^ ((r&7)<<4) of row r.
#pragma unroll
    for (int j = 0; j < 8; ++j) {
        const int r = 2 * j + (l >> 5);                       // local row 0..15
        const int cob = ((l & 31) * 16) ^ ((r & 7) << 4);     // bytes in 512B window
        const float* g = x + (size_t)(row0 + r) * XD + w * 128 + (cob >> 2);
        float* dst = &xbuf[w][2 * j][0];                      // wave-uniform base
        load_lds16(g, dst);
    }
    // Wave-local drain: no __syncthreads -- each wave proceeds independently.
    asm volatile("s_waitcnt vmcnt(0)" ::: "memory");
    __builtin_amdgcn_sched_barrier(0);

    // ---- compute: wave w -> i-tiles 4w .. 4w+3 ----
    f32x4 c4[4];
#pragma unroll
    for (int t = 0; t < 4; ++t) c4[t] = f32x4{0.f, 0.f, 0.f, 0.f};
    float z = 0.f;

    const short8* bhp = (const short8*)bh;
    const char* panel = (const char*)&xbuf[w][0][0];
    const int swz = (m & 7) << 4;
    const int oa = (q * 32) ^ swz;            // xa byte offset within 128B chunk
    const int ob = (q * 32 + 16) ^ swz;       // xb byte offset within 128B chunk

#pragma unroll
    for (int ii = 0; ii < 4; ++ii) {
        const int it = w * 4 + ii;
        const int col = it * 32 + q * 8;
        const size_t fbase = (size_t)(it * 4) * 64 + l;

        // A source: row m, logical floats ii*32+q*8 .. +7 of this wave's panel.
        const int chunk = m * 512 + ii * 128;
        f32x4 xa = *(const f32x4*)(panel + chunk + oa);
        f32x4 xb = *(const f32x4*)(panel + chunk + ob);

        // w source: 4 KB wc, L2/L1-hot (read by every block).
        f32x4 wa = *(const f32x4*)(wc + col);
        f32x4 wb = *(const f32x4*)(wc + col + 4);

        float xs[8] = {xa.x, xa.y, xa.z, xa.w, xb.x, xb.y, xb.z, xb.w};
        z = fmaf(xs[0]*xs[0], wa.x, z); z = fmaf(xs[1]*xs[1], wa.y, z);
        z = fmaf(xs[2]*xs[2], wa.z, z); z = fmaf(xs[3]*xs[3], wa.w, z);
        z = fmaf(xs[4]*xs[4], wb.x, z); z = fmaf(xs[5]*xs[5], wb.y, z);
        z = fmaf(xs[6]*xs[6], wb.z, z); z = fmaf(xs[7]*xs[7], wb.w, z);

        // RNE bf16 pack of x (pairwise via v_perm)
        unsigned ahp[4];
#pragma unroll
        for (int jp = 0; jp < 4; ++jp) {
            unsigned u0 = fbits(xs[2 * jp]);
            unsigned u1 = fbits(xs[2 * jp + 1]);
            u0 += 0x7FFFu + ((u0 >> 16) & 1u);
            u1 += 0x7FFFu + ((u1 >> 16) & 1u);
            ahp[jp] = __builtin_amdgcn_perm(u1, u0, 0x07060302u);  // {hi16(u1),hi16(u0)}
        }
        short8 ah;
#pragma unroll
        for (int jp = 0; jp < 4; ++jp) {
            ah[2*jp]   = (short)(ahp[jp] & 0xFFFF);
            ah[2*jp+1] = (short)(ahp[jp] >> 16);
        }

        // 4 independent MFMA chains (one per col-tile t)
#pragma unroll
        for (int t = 0; t < 4; ++t) {
            short8 vh = bhp[fbase + (size_t)t * 64];
            c4[t] = __builtin_amdgcn_mfma_f32_16x16x32_bf16(ah, vh, c4[t], 0, 0, 0);
        }
    }

    // z: sum over q-chunks -> full-q partial z for row m (this wave's i-range)
    z += __shfl_xor(z, 16);
    z += __shfl_xor(z, 32);

    __syncthreads();   // all panels consumed; front of xbuf becomes combine area
    float* comb = &xbuf[0][0][0];   // 7 x 64 x 17 floats = 30464 B <= 65536 B

    if (w > 0) {
        const int s = w - 1;
#pragma unroll
        for (int t = 0; t < 4; ++t)
#pragma unroll
            for (int r = 0; r < 4; ++r) comb[(s * 64 + l) * 17 + t * 4 + r] = c4[t][r];
        if (l < 16) zb[s][l] = z;
    }
    __syncthreads();

    if (w == 0) {
#pragma unroll
        for (int s = 0; s < 7; ++s) {
#pragma unroll
            for (int t = 0; t < 4; ++t)
#pragma unroll
                for (int r = 0; r < 4; ++r) c4[t][r] += comb[(s * 64 + l) * 17 + t * 4 + r];
            z += zb[s][m];
        }

        // C layout: col = l&15, row = q*4 + reg
        float p[4] = {0.f, 0.f, 0.f, 0.f};
#pragma unroll
        for (int r = 0; r < 4; ++r)
#pragma unroll
            for (int t = 0; t < 4; ++t) p[r] = fmaf(c4[t][r], c4[t][r], p[r]);
#pragma unroll
        for (int mask = 1; mask < 16; mask <<= 1)
#pragma unroll
            for (int r = 0; r < 4; ++r) p[r] += __shfl_xor(p[r], mask);

        float zrow = __shfl(z, q * 4 + m, 16);
        if (m < 4) out[row0 + q * 4 + m] = 0.5f * (p[m] - zrow);
    }
}

extern "C" void kernel_launch(void* const* d_in, const int* in_sizes, int n_in,
                              void* d_out, int out_size, void* d_ws, size_t ws_size,
                              hipStream_t stream) {
    const float* x = (const float*)d_in[0];      // (16384, 1024) fp32
    const float* v = (const float*)d_in[1];      // (1024, 64) fp32
    float* out = (float*)d_out;                  // (16384, 1) fp32

    unsigned short* bh = (unsigned short*)d_ws;                    // 131072 B
    float* wc = (float*)((char*)d_ws + 131072);                    //   4096 B

    const int B = in_sizes[0] / XD;              // 16384

    hipLaunchKernelGGL(prep_kernel, dim3(36), dim3(256), 0, stream, v, bh, wc);
    hipLaunchKernelGGL(cross_r19, dim3(B / 16), dim3(512), 0, stream,
                       x, bh, wc, out);
}